// Round 1
// baseline (903.107 us; speedup 1.0000x reference)
//
#include <hip/hip_runtime.h>
#include <hip/hip_bf16.h>
#include <math.h>

#define G 4
#define S 2048
#define MDIM 1024
#define E 8
#define HDIM 4096
#define TOPK 2
#define CAP 640
#define GC (G*CAP)      /* 2560 rows per expert */

typedef __attribute__((ext_vector_type(8))) short bf16x8;
typedef __attribute__((ext_vector_type(4))) float f32x4;
typedef unsigned int u32;
typedef unsigned short u16;

__device__ __forceinline__ u16 f2bf(float f) {
    union { float f; u32 u; } v; v.f = f;
    u32 r = v.u + 0x7fffu + ((v.u >> 16) & 1u);
    return (u16)(r >> 16);
}

__device__ __forceinline__ void gload16(const u16* gp, u16* lp) {
    __builtin_amdgcn_global_load_lds((const __attribute__((address_space(1))) u32*)gp,
                                     (__attribute__((address_space(3))) u32*)lp,
                                     16, 0, 0);
}

// ---------------- weight transpose + f32->bf16 convert ----------------
// in: [E][R][C] f32   out: [E][C][R] bf16
__global__ __launch_bounds__(256) void transpose_cvt(const float* __restrict__ in,
                                                     u16* __restrict__ out, int R, int C) {
    int e = blockIdx.z;
    const float* ine = in + (size_t)e * R * C;
    u16* oute = out + (size_t)e * R * C;
    __shared__ float tile[32][33];
    int tx = threadIdx.x, ty = threadIdx.y;
    int x0 = blockIdx.x * 32, y0 = blockIdx.y * 32;
    #pragma unroll
    for (int i = 0; i < 4; ++i)
        tile[ty + i*8][tx] = ine[(size_t)(y0 + ty + i*8) * C + x0 + tx];
    __syncthreads();
    #pragma unroll
    for (int i = 0; i < 4; ++i)
        oute[(size_t)(x0 + ty + i*8) * R + y0 + tx] = f2bf(tile[tx][ty + i*8]);
}

// ---------------- router: logits, softmax, top-2, aux partials ----------------
__global__ __launch_bounds__(256) void router_kernel(const float* __restrict__ inp,
                                                     const float* __restrict__ rw,
                                                     int* __restrict__ top_i,
                                                     float* __restrict__ top_p,
                                                     float* __restrict__ partials) {
    int wid = threadIdx.x >> 6, lane = threadIdx.x & 63;
    int tok = blockIdx.x * 4 + wid;                 // 0..16383
    const float* x = inp + (size_t)tok * MDIM;
    float acc[E] = {0.f,0.f,0.f,0.f,0.f,0.f,0.f,0.f};
    #pragma unroll
    for (int rep = 0; rep < 4; ++rep) {
        int m0 = rep * 256 + lane * 4;
        f32x4 xv = *(const f32x4*)(x + m0);
        #pragma unroll
        for (int j = 0; j < 4; ++j) {
            const float* r = rw + (size_t)(m0 + j) * E;
            float xj = xv[j];
            #pragma unroll
            for (int e = 0; e < E; ++e) acc[e] += xj * r[e];
        }
    }
    #pragma unroll
    for (int e = 0; e < E; ++e)
        #pragma unroll
        for (int off = 32; off; off >>= 1) acc[e] += __shfl_down(acc[e], off);

    __shared__ float part[4][17];
    if (lane == 0) {
        float mx = acc[0];
        #pragma unroll
        for (int e = 1; e < E; ++e) mx = fmaxf(mx, acc[e]);
        float p[E], sum = 0.f;
        #pragma unroll
        for (int e = 0; e < E; ++e) { p[e] = expf(acc[e] - mx); sum += p[e]; }
        float inv = 1.f / sum;
        #pragma unroll
        for (int e = 0; e < E; ++e) p[e] *= inv;
        float lse = logf(sum) + mx;
        int i0 = 0;
        #pragma unroll
        for (int e = 1; e < E; ++e) if (acc[e] > acc[i0]) i0 = e;
        int i1 = (i0 == 0) ? 1 : 0;
        #pragma unroll
        for (int e = 0; e < E; ++e) if (e != i0 && acc[e] > acc[i1]) i1 = e;
        top_i[tok*2+0] = i0; top_i[tok*2+1] = i1;
        top_p[tok*2+0] = p[i0]; top_p[tok*2+1] = p[i1];
        #pragma unroll
        for (int e = 0; e < E; ++e) { part[wid][e] = p[e]; part[wid][8+e] = 0.f; }
        part[wid][8+i0] = 1.f; part[wid][8+i1] = 1.f;
        part[wid][16] = lse * lse;
    }
    __syncthreads();
    if (threadIdx.x < 17) {
        float v = part[0][threadIdx.x] + part[1][threadIdx.x] +
                  part[2][threadIdx.x] + part[3][threadIdx.x];
        partials[(size_t)blockIdx.x * 17 + threadIdx.x] = v;
    }
}

__global__ __launch_bounds__(256) void reduce_partials(const float* __restrict__ partials,
                                                       float* __restrict__ sums) {
    int g = blockIdx.x, t = threadIdx.x;
    float loc[17];
    #pragma unroll
    for (int c = 0; c < 17; ++c) loc[c] = 0.f;
    for (int r = t; r < 1024; r += 256) {
        const float* pr = partials + ((size_t)g * 1024 + r) * 17;
        #pragma unroll
        for (int c = 0; c < 17; ++c) loc[c] += pr[c];
    }
    __shared__ float red[256];
    for (int c = 0; c < 17; ++c) {
        red[t] = loc[c]; __syncthreads();
        for (int off = 128; off; off >>= 1) {
            if (t < off) red[t] += red[t + off];
            __syncthreads();
        }
        if (t == 0) sums[g * 17 + c] = red[0];
        __syncthreads();
    }
}

__global__ void aux_final(const float* __restrict__ sums, float* __restrict__ out) {
    float lb = 0.f, z = 0.f;
    for (int g = 0; g < G; ++g) {
        for (int e = 0; e < E; ++e)
            lb += (sums[g*17 + 8 + e] / (float)S) * (sums[g*17 + e] / (float)S);
        z += sums[g*17 + 16];
    }
    lb = lb / (float)(G * E) * (float)(E * E);
    z /= (float)(G * S);
    out[(size_t)G * S * MDIM] = 0.01f * lb + 0.001f * z;
}

// ---------------- capacity scan (one block per (g,e)) ----------------
__global__ __launch_bounds__(256) void scan_kernel(const int* __restrict__ top_i,
                                                   const float* __restrict__ pad,
                                                   int* __restrict__ slot_token,
                                                   int* __restrict__ token_c) {
    int b = blockIdx.x; int g = b >> 3, e = b & 7;
    int t = threadIdx.x;
    __shared__ int sums[256];
    int base = t * 16;
    int run = 0; unsigned mask16 = 0; int loc[16];
    #pragma unroll
    for (int j = 0; j < 16; ++j) {
        int i = base + j; int s = i >> 1, k = i & 1;
        int ex = top_i[((size_t)(g * S + s)) * 2 + k];
        int m = (ex == e) && (pad[g * S + s] == 0.f);
        run += m; loc[j] = run; mask16 |= ((unsigned)m << j);
    }
    sums[t] = run; __syncthreads();
    for (int off = 1; off < 256; off <<= 1) {
        int v = (t >= off) ? sums[t - off] : 0;
        __syncthreads();
        sums[t] += v;
        __syncthreads();
    }
    int excl = sums[t] - run;
    #pragma unroll
    for (int j = 0; j < 16; ++j) {
        if ((mask16 >> j) & 1u) {
            int pos = excl + loc[j];
            if (pos <= CAP) {
                int i = base + j; int s = i >> 1, k = i & 1;
                slot_token[((size_t)(e * G + g)) * CAP + (pos - 1)] = s;
                token_c[((size_t)(g * S + s)) * 2 + k] = pos - 1;
            }
        }
    }
}

// ---------------- gather tokens -> X bf16 [E][GC][MDIM] ----------------
__global__ __launch_bounds__(128) void gather_kernel(const float* __restrict__ inp,
                                                     const int* __restrict__ slot_token,
                                                     u16* __restrict__ X) {
    int row = blockIdx.x;              // e*GC + g*CAP + c
    int t = threadIdx.x;               // 128 threads * 8 elems
    int s = slot_token[row];
    int g = (row % GC) / CAP;
    bf16x8 v;
    if (s >= 0) {
        const float* src = inp + ((size_t)(g * S + s)) * MDIM + t * 8;
        f32x4 a = *(const f32x4*)src;
        f32x4 b = *(const f32x4*)(src + 4);
        #pragma unroll
        for (int j = 0; j < 4; ++j) { v[j] = (short)f2bf(a[j]); v[4+j] = (short)f2bf(b[j]); }
    } else {
        #pragma unroll
        for (int j = 0; j < 8; ++j) v[j] = 0;
    }
    *(bf16x8*)(X + (size_t)row * MDIM + t * 8) = v;
}

// ---------------- GEMM1+2 fused: H = silu(X*WgT^T) * (X*W0T^T), bf16 out ----------------
__global__ __launch_bounds__(256, 2) void gemm_ffn12(const u16* __restrict__ Xb,
                                                     const u16* __restrict__ WgT,
                                                     const u16* __restrict__ W0T,
                                                     u16* __restrict__ Hb) {
    int mt = blockIdx.x, nt = blockIdx.y, e = blockIdx.z;
    const u16* A  = Xb  + (size_t)e * GC * MDIM  + (size_t)mt * 128 * MDIM;
    const u16* Bg = WgT + (size_t)e * HDIM * MDIM + (size_t)nt * 128 * MDIM;
    const u16* B0 = W0T + (size_t)e * HDIM * MDIM + (size_t)nt * 128 * MDIM;
    __shared__ u16 at[128 * 32], bgt[128 * 32], b0t[128 * 32];
    int tid = threadIdx.x, w = tid >> 6, l = tid & 63;
    int wm = w >> 1, wn = w & 1;
    f32x4 accg[4][4], acc0[4][4];
    #pragma unroll
    for (int i = 0; i < 4; ++i)
        #pragma unroll
        for (int j = 0; j < 4; ++j) { accg[i][j] = (f32x4){0,0,0,0}; acc0[i][j] = (f32x4){0,0,0,0}; }
    int rs = l >> 2, co = (l & 3) * 8;
    int abyte = (wm*64 + (l & 15)) * 64 + (l >> 4) * 16;
    int bbyte = (wn*64 + (l & 15)) * 64 + (l >> 4) * 16;

    for (int kt = 0; kt < MDIM / 32; ++kt) {
        int k0 = kt * 32;
        __syncthreads();
        #pragma unroll
        for (int i = 0; i < 2; ++i) {
            int r = w*32 + i*16 + rs;
            u16* ldsrow_a = at  + (size_t)(w*32 + i*16) * 32;
            u16* ldsrow_g = bgt + (size_t)(w*32 + i*16) * 32;
            u16* ldsrow_0 = b0t + (size_t)(w*32 + i*16) * 32;
            gload16(A  + (size_t)r * MDIM + k0 + co, ldsrow_a);
            gload16(Bg + (size_t)r * MDIM + k0 + co, ldsrow_g);
            gload16(B0 + (size_t)r * MDIM + k0 + co, ldsrow_0);
        }
        __syncthreads();
        bf16x8 af[4], bgf[4], b0f[4];
        #pragma unroll
        for (int f = 0; f < 4; ++f) {
            af[f]  = *(const bf16x8*)((const char*)at  + abyte + f * 1024);
            bgf[f] = *(const bf16x8*)((const char*)bgt + bbyte + f * 1024);
            b0f[f] = *(const bf16x8*)((const char*)b0t + bbyte + f * 1024);
        }
        #pragma unroll
        for (int fm = 0; fm < 4; ++fm)
            #pragma unroll
            for (int fn = 0; fn < 4; ++fn) {
                accg[fm][fn] = __builtin_amdgcn_mfma_f32_16x16x32_bf16(af[fm], bgf[fn], accg[fm][fn], 0, 0, 0);
                acc0[fm][fn] = __builtin_amdgcn_mfma_f32_16x16x32_bf16(af[fm], b0f[fn], acc0[fm][fn], 0, 0, 0);
            }
    }
    size_t ob = (size_t)e * GC * HDIM;
    int row0 = mt*128 + wm*64, col0 = nt*128 + wn*64 + (l & 15);
    int rb = (l >> 4) * 4;
    #pragma unroll
    for (int fm = 0; fm < 4; ++fm)
        #pragma unroll
        for (int fn = 0; fn < 4; ++fn)
            #pragma unroll
            for (int r = 0; r < 4; ++r) {
                float gv = accg[fm][fn][r], vv = acc0[fm][fn][r];
                float hv = gv / (1.f + __expf(-gv)) * vv;
                Hb[ob + (size_t)(row0 + fm*16 + rb + r) * HDIM + col0 + fn*16] = f2bf(hv);
            }
}

// ---------------- GEMM3: EO = H * WoT^T, f32 out ----------------
__global__ __launch_bounds__(256, 2) void gemm_out(const u16* __restrict__ Hb,
                                                   const u16* __restrict__ WoT,
                                                   float* __restrict__ EO) {
    int mt = blockIdx.x, nt = blockIdx.y, e = blockIdx.z;
    const u16* A = Hb  + (size_t)e * GC * HDIM   + (size_t)mt * 128 * HDIM;
    const u16* B = WoT + (size_t)e * MDIM * HDIM + (size_t)nt * 128 * HDIM;
    __shared__ u16 at[128 * 32], bt[128 * 32];
    int tid = threadIdx.x, w = tid >> 6, l = tid & 63;
    int wm = w >> 1, wn = w & 1;
    f32x4 acc[4][4];
    #pragma unroll
    for (int i = 0; i < 4; ++i)
        #pragma unroll
        for (int j = 0; j < 4; ++j) acc[i][j] = (f32x4){0,0,0,0};
    int rs = l >> 2, co = (l & 3) * 8;
    int abyte = (wm*64 + (l & 15)) * 64 + (l >> 4) * 16;
    int bbyte = (wn*64 + (l & 15)) * 64 + (l >> 4) * 16;

    for (int kt = 0; kt < HDIM / 32; ++kt) {
        int k0 = kt * 32;
        __syncthreads();
        #pragma unroll
        for (int i = 0; i < 2; ++i) {
            int r = w*32 + i*16 + rs;
            gload16(A + (size_t)r * HDIM + k0 + co, at + (size_t)(w*32 + i*16) * 32);
            gload16(B + (size_t)r * HDIM + k0 + co, bt + (size_t)(w*32 + i*16) * 32);
        }
        __syncthreads();
        bf16x8 af[4], bf[4];
        #pragma unroll
        for (int f = 0; f < 4; ++f) {
            af[f] = *(const bf16x8*)((const char*)at + abyte + f * 1024);
            bf[f] = *(const bf16x8*)((const char*)bt + bbyte + f * 1024);
        }
        #pragma unroll
        for (int fm = 0; fm < 4; ++fm)
            #pragma unroll
            for (int fn = 0; fn < 4; ++fn)
                acc[fm][fn] = __builtin_amdgcn_mfma_f32_16x16x32_bf16(af[fm], bf[fn], acc[fm][fn], 0, 0, 0);
    }
    size_t ob = (size_t)e * GC * MDIM;
    int row0 = mt*128 + wm*64, col0 = nt*128 + wn*64 + (l & 15);
    int rb = (l >> 4) * 4;
    #pragma unroll
    for (int fm = 0; fm < 4; ++fm)
        #pragma unroll
        for (int fn = 0; fn < 4; ++fn)
            #pragma unroll
            for (int r = 0; r < 4; ++r)
                EO[ob + (size_t)(row0 + fm*16 + rb + r) * MDIM + col0 + fn*16] = acc[fm][fn][r];
}

// ---------------- combine: out[g,s,:] = sum_k p_k * EO[e_k, g*CAP+c_k, :] ----------------
__global__ __launch_bounds__(256) void combine_kernel(const float* __restrict__ EO,
                                                      const int* __restrict__ top_i,
                                                      const float* __restrict__ top_p,
                                                      const int* __restrict__ token_c,
                                                      float* __restrict__ out) {
    int tok = blockIdx.x, t = threadIdx.x;
    int g = tok >> 11;
    f32x4 acc = {0.f, 0.f, 0.f, 0.f};
    #pragma unroll
    for (int k = 0; k < 2; ++k) {
        int c = token_c[tok * 2 + k];
        if (c >= 0) {
            int e = top_i[tok * 2 + k];
            float p = top_p[tok * 2 + k];
            const float* src = EO + ((size_t)e * GC + g * CAP + c) * MDIM + t * 4;
            f32x4 v = *(const f32x4*)src;
            #pragma unroll
            for (int j = 0; j < 4; ++j) acc[j] += p * v[j];
        }
    }
    *(f32x4*)(out + (size_t)tok * MDIM + t * 4) = acc;
}

extern "C" void kernel_launch(void* const* d_in, const int* in_sizes, int n_in,
                              void* d_out, int out_size, void* d_ws, size_t ws_size,
                              hipStream_t stream) {
    (void)in_sizes; (void)n_in; (void)out_size; (void)ws_size;
    const float* inputs   = (const float*)d_in[0];
    const float* paddings = (const float*)d_in[1];
    const float* router_w = (const float*)d_in[2];
    const float* wi_gate  = (const float*)d_in[3];
    const float* wi_0     = (const float*)d_in[4];
    const float* wo       = (const float*)d_in[5];
    float* out = (float*)d_out;

    char* p = (char*)d_ws;
    u16* WgT = (u16*)p; p += (size_t)E * HDIM * MDIM * 2;
    u16* W0T = (u16*)p; p += (size_t)E * HDIM * MDIM * 2;
    u16* WoT = (u16*)p; p += (size_t)E * HDIM * MDIM * 2;
    u16* Xb  = (u16*)p; p += (size_t)E * GC * MDIM * 2;
    u16* Hb  = (u16*)p; p += (size_t)E * GC * HDIM * 2;
    float* EO = (float*)p; p += (size_t)E * GC * MDIM * 4;
    int*   top_i = (int*)p;   p += (size_t)G * S * TOPK * 4;
    float* top_p = (float*)p; p += (size_t)G * S * TOPK * 4;
    int*   token_c = (int*)p; p += (size_t)G * S * TOPK * 4;
    int*   slot_token = (int*)p; p += (size_t)E * G * CAP * 4;
    float* partials = (float*)p; p += (size_t)4096 * 17 * 4;
    float* sums = (float*)p; p += 4 * 17 * 4;

    hipMemsetAsync(token_c, 0xFF, (size_t)G * S * TOPK * 4, stream);
    hipMemsetAsync(slot_token, 0xFF, (size_t)E * G * CAP * 4, stream);

    transpose_cvt<<<dim3(HDIM/32, MDIM/32, E), dim3(32, 8), 0, stream>>>(wi_gate, WgT, MDIM, HDIM);
    transpose_cvt<<<dim3(HDIM/32, MDIM/32, E), dim3(32, 8), 0, stream>>>(wi_0,   W0T, MDIM, HDIM);
    transpose_cvt<<<dim3(MDIM/32, HDIM/32, E), dim3(32, 8), 0, stream>>>(wo,     WoT, HDIM, MDIM);

    router_kernel<<<G * S / 4, 256, 0, stream>>>(inputs, router_w, top_i, top_p, partials);
    reduce_partials<<<G, 256, 0, stream>>>(partials, sums);
    scan_kernel<<<G * E, 256, 0, stream>>>(top_i, paddings, slot_token, token_c);
    gather_kernel<<<E * GC, 128, 0, stream>>>(inputs, slot_token, Xb);
    gemm_ffn12<<<dim3(GC/128, HDIM/128, E), 256, 0, stream>>>(Xb, WgT, W0T, Hb);
    gemm_out<<<dim3(GC/128, MDIM/128, E), 256, 0, stream>>>(Hb, WoT, EO);
    combine_kernel<<<G * S, 256, 0, stream>>>(EO, top_i, top_p, token_c, out);
    aux_final<<<1, 1, 0, stream>>>(sums, out);
}

// Round 2
// 832.903 us; speedup vs baseline: 1.0843x; 1.0843x over previous
//
#include <hip/hip_runtime.h>
#include <hip/hip_bf16.h>
#include <math.h>

#define G 4
#define S 2048
#define MDIM 1024
#define E 8
#define HDIM 4096
#define TOPK 2
#define CAP 640
#define GC (G*CAP)      /* 2560 rows per expert */

typedef __attribute__((ext_vector_type(8))) short bf16x8;
typedef __attribute__((ext_vector_type(4))) short s16x4;
typedef __attribute__((ext_vector_type(4))) float f32x4;
typedef unsigned int u32;
typedef unsigned short u16;

#define MFMA16(a,b,c) __builtin_amdgcn_mfma_f32_16x16x32_bf16(a,b,c,0,0,0)

__device__ __forceinline__ u16 f2bf(float f) {
    union { float f; u32 u; } v; v.f = f;
    u32 r = v.u + 0x7fffu + ((v.u >> 16) & 1u);
    return (u16)(r >> 16);
}

__device__ __forceinline__ void gload16(const char* gp, char* lp) {
    __builtin_amdgcn_global_load_lds((const __attribute__((address_space(1))) u32*)gp,
                                     (__attribute__((address_space(3))) u32*)lp,
                                     16, 0, 0);
}

// swizzle for 64-byte LDS rows: spreads 8 consecutive rows across 8 distinct
// 16B bank slots (2-way alias at 16 rows = free). Involution (XOR).
__device__ __forceinline__ int swzb(int r) { return ((r >> 1) & 3) << 4; }

// ---------------- weight transpose + f32->bf16 convert ----------------
__global__ __launch_bounds__(256) void transpose_cvt(const float* __restrict__ in,
                                                     u16* __restrict__ out, int R, int C) {
    int e = blockIdx.z;
    const float* ine = in + (size_t)e * R * C;
    u16* oute = out + (size_t)e * R * C;
    __shared__ float tile[32][33];
    int tx = threadIdx.x, ty = threadIdx.y;
    int x0 = blockIdx.x * 32, y0 = blockIdx.y * 32;
    #pragma unroll
    for (int i = 0; i < 4; ++i)
        tile[ty + i*8][tx] = ine[(size_t)(y0 + ty + i*8) * C + x0 + tx];
    __syncthreads();
    #pragma unroll
    for (int i = 0; i < 4; ++i)
        oute[(size_t)(x0 + ty + i*8) * R + y0 + tx] = f2bf(tile[tx][ty + i*8]);
}

// ---------------- router ----------------
__global__ __launch_bounds__(256) void router_kernel(const float* __restrict__ inp,
                                                     const float* __restrict__ rw,
                                                     int* __restrict__ top_i,
                                                     float* __restrict__ top_p,
                                                     float* __restrict__ partials) {
    int wid = threadIdx.x >> 6, lane = threadIdx.x & 63;
    int tok = blockIdx.x * 4 + wid;
    const float* x = inp + (size_t)tok * MDIM;
    float acc[E] = {0.f,0.f,0.f,0.f,0.f,0.f,0.f,0.f};
    #pragma unroll
    for (int rep = 0; rep < 4; ++rep) {
        int m0 = rep * 256 + lane * 4;
        f32x4 xv = *(const f32x4*)(x + m0);
        #pragma unroll
        for (int j = 0; j < 4; ++j) {
            const float* r = rw + (size_t)(m0 + j) * E;
            float xj = xv[j];
            #pragma unroll
            for (int e = 0; e < E; ++e) acc[e] += xj * r[e];
        }
    }
    #pragma unroll
    for (int e = 0; e < E; ++e)
        #pragma unroll
        for (int off = 32; off; off >>= 1) acc[e] += __shfl_down(acc[e], off);

    __shared__ float part[4][17];
    if (lane == 0) {
        float mx = acc[0];
        #pragma unroll
        for (int e = 1; e < E; ++e) mx = fmaxf(mx, acc[e]);
        float p[E], sum = 0.f;
        #pragma unroll
        for (int e = 0; e < E; ++e) { p[e] = expf(acc[e] - mx); sum += p[e]; }
        float inv = 1.f / sum;
        #pragma unroll
        for (int e = 0; e < E; ++e) p[e] *= inv;
        float lse = logf(sum) + mx;
        int i0 = 0;
        #pragma unroll
        for (int e = 1; e < E; ++e) if (acc[e] > acc[i0]) i0 = e;
        int i1 = (i0 == 0) ? 1 : 0;
        #pragma unroll
        for (int e = 0; e < E; ++e) if (e != i0 && acc[e] > acc[i1]) i1 = e;
        top_i[tok*2+0] = i0; top_i[tok*2+1] = i1;
        top_p[tok*2+0] = p[i0]; top_p[tok*2+1] = p[i1];
        #pragma unroll
        for (int e = 0; e < E; ++e) { part[wid][e] = p[e]; part[wid][8+e] = 0.f; }
        part[wid][8+i0] = 1.f; part[wid][8+i1] = 1.f;
        part[wid][16] = lse * lse;
    }
    __syncthreads();
    if (threadIdx.x < 17) {
        float v = part[0][threadIdx.x] + part[1][threadIdx.x] +
                  part[2][threadIdx.x] + part[3][threadIdx.x];
        partials[(size_t)blockIdx.x * 17 + threadIdx.x] = v;
    }
}

__global__ __launch_bounds__(256) void reduce_partials(const float* __restrict__ partials,
                                                       float* __restrict__ sums) {
    int g = blockIdx.x, t = threadIdx.x;
    float loc[17];
    #pragma unroll
    for (int c = 0; c < 17; ++c) loc[c] = 0.f;
    for (int r = t; r < 1024; r += 256) {
        const float* pr = partials + ((size_t)g * 1024 + r) * 17;
        #pragma unroll
        for (int c = 0; c < 17; ++c) loc[c] += pr[c];
    }
    __shared__ float red[256];
    for (int c = 0; c < 17; ++c) {
        red[t] = loc[c]; __syncthreads();
        for (int off = 128; off; off >>= 1) {
            if (t < off) red[t] += red[t + off];
            __syncthreads();
        }
        if (t == 0) sums[g * 17 + c] = red[0];
        __syncthreads();
    }
}

__global__ void aux_final(const float* __restrict__ sums, float* __restrict__ out) {
    float lb = 0.f, z = 0.f;
    for (int g = 0; g < G; ++g) {
        for (int e = 0; e < E; ++e)
            lb += (sums[g*17 + 8 + e] / (float)S) * (sums[g*17 + e] / (float)S);
        z += sums[g*17 + 16];
    }
    lb = lb / (float)(G * E) * (float)(E * E);
    z /= (float)(G * S);
    out[(size_t)G * S * MDIM] = 0.01f * lb + 0.001f * z;
}

// ---------------- capacity scan ----------------
__global__ __launch_bounds__(256) void scan_kernel(const int* __restrict__ top_i,
                                                   const float* __restrict__ pad,
                                                   int* __restrict__ slot_token,
                                                   int* __restrict__ token_c) {
    int b = blockIdx.x; int g = b >> 3, e = b & 7;
    int t = threadIdx.x;
    __shared__ int sums[256];
    int base = t * 16;
    int run = 0; unsigned mask16 = 0; int loc[16];
    #pragma unroll
    for (int j = 0; j < 16; ++j) {
        int i = base + j; int s = i >> 1, k = i & 1;
        int ex = top_i[((size_t)(g * S + s)) * 2 + k];
        int m = (ex == e) && (pad[g * S + s] == 0.f);
        run += m; loc[j] = run; mask16 |= ((unsigned)m << j);
    }
    sums[t] = run; __syncthreads();
    for (int off = 1; off < 256; off <<= 1) {
        int v = (t >= off) ? sums[t - off] : 0;
        __syncthreads();
        sums[t] += v;
        __syncthreads();
    }
    int excl = sums[t] - run;
    #pragma unroll
    for (int j = 0; j < 16; ++j) {
        if ((mask16 >> j) & 1u) {
            int pos = excl + loc[j];
            if (pos <= CAP) {
                int i = base + j; int s = i >> 1, k = i & 1;
                slot_token[((size_t)(e * G + g)) * CAP + (pos - 1)] = s;
                token_c[((size_t)(g * S + s)) * 2 + k] = pos - 1;
            }
        }
    }
}

// ---------------- gather tokens -> X bf16 [E][GC][MDIM] ----------------
__global__ __launch_bounds__(128) void gather_kernel(const float* __restrict__ inp,
                                                     const int* __restrict__ slot_token,
                                                     u16* __restrict__ X) {
    int row = blockIdx.x;
    int t = threadIdx.x;
    int s = slot_token[row];
    int g = (row % GC) / CAP;
    bf16x8 v;
    if (s >= 0) {
        const float* src = inp + ((size_t)(g * S + s)) * MDIM + t * 8;
        f32x4 a = *(const f32x4*)src;
        f32x4 b = *(const f32x4*)(src + 4);
        #pragma unroll
        for (int j = 0; j < 4; ++j) { v[j] = (short)f2bf(a[j]); v[4+j] = (short)f2bf(b[j]); }
    } else {
        #pragma unroll
        for (int j = 0; j < 8; ++j) v[j] = 0;
    }
    *(bf16x8*)(X + (size_t)row * MDIM + t * 8) = v;
}

// ======================================================================
// GEMM1+2 fused, pipelined: BM=256 BN=128 BK=32, ring-4 LDS, counted vmcnt.
// H = silu(X*Wg^T) * (X*W0^T), bf16 out. mfma(B,A,acc) -> lane holds 4
// consecutive N cols per acc reg (packed 8B stores).
// LDS: A 4x16KB @0, Bg 4x8KB @65536, B0 4x8KB @98304 = 128 KiB.
// ======================================================================
__global__ __launch_bounds__(512, 2) void gemm_ffn12_v2(
        const u16* __restrict__ Xb, const u16* __restrict__ WgT,
        const u16* __restrict__ W0T, u16* __restrict__ Hb) {
    extern __shared__ char smem[];
    const int NK = MDIM / 32;                      // 32
    int bid = blockIdx.x;
    int swz = (bid & 7) * 320 + (bid >> 3);        // 2560 % 8 == 0, bijective
    int mt = swz % 10, nt = (swz / 10) & 31, e = swz / 320;
    const char* A  = (const char*)(Xb  + (size_t)e * GC * MDIM   + (size_t)mt * 256 * MDIM);
    const char* Bg = (const char*)(WgT + (size_t)e * HDIM * MDIM + (size_t)nt * 128 * MDIM);
    const char* B0 = (const char*)(W0T + (size_t)e * HDIM * MDIM + (size_t)nt * 128 * MDIM);
    int tid = threadIdx.x, w = tid >> 6, l = tid & 63;
    int wm = w >> 2, wn = w & 3;                   // 2M x 4N waves
    int rl = l >> 2, cch = (l & 3) * 16;           // stage: row-in-16, byte chunk
    int fr = l & 15, fg = l >> 4;                  // frag: free-dim row, k-group

    f32x4 ag[8][2], ao[8][2];
    #pragma unroll
    for (int i = 0; i < 8; ++i) {
        ag[i][0] = (f32x4){0,0,0,0}; ag[i][1] = (f32x4){0,0,0,0};
        ao[i][0] = (f32x4){0,0,0,0}; ao[i][1] = (f32x4){0,0,0,0};
    }

    auto stageA = [&](int t) {                     // 2 loads/thread
        char* dst = smem + (t & 3) * 16384;
        #pragma unroll
        for (int i = 0; i < 2; ++i) {
            int r = (i * 8 + w) * 16 + rl;
            gload16(A + ((size_t)r * MDIM + t * 32) * 2 + (cch ^ swzb(r)),
                    dst + (i * 8 + w) * 1024);
        }
    };
    auto stageB = [&](int t) {                     // 2 loads/thread (Bg+B0)
        int r = w * 16 + rl;
        gload16(Bg + ((size_t)r * MDIM + t * 32) * 2 + (cch ^ swzb(r)),
                smem + 65536 + (t & 3) * 8192 + w * 1024);
        gload16(B0 + ((size_t)r * MDIM + t * 32) * 2 + (cch ^ swzb(r)),
                smem + 98304 + (t & 3) * 8192 + w * 1024);
    };
    auto ldA = [&](int fm, int t) -> bf16x8 {
        int r = wm * 128 + fm * 16 + fr;
        return *(const bf16x8*)(smem + (t & 3) * 16384 + r * 64 + ((fg * 16) ^ swzb(r)));
    };
    auto ldG = [&](int fn, int t) -> bf16x8 {
        int r = wn * 32 + fn * 16 + fr;
        return *(const bf16x8*)(smem + 65536 + (t & 3) * 8192 + r * 64 + ((fg * 16) ^ swzb(r)));
    };
    auto ldO = [&](int fn, int t) -> bf16x8 {
        int r = wn * 32 + fn * 16 + fr;
        return *(const bf16x8*)(smem + 98304 + (t & 3) * 8192 + r * 64 + ((fg * 16) ^ swzb(r)));
    };

    // prologue: stage K-tiles 0,1 (8 loads); wait tile-0 (leave tile-1's 4 in flight)
    stageA(0); stageB(0);
    stageA(1); stageB(1);
    asm volatile("s_waitcnt vmcnt(4)" ::: "memory");
    __builtin_amdgcn_s_barrier();

    #pragma unroll 1
    for (int t = 0; t < NK; ++t) {
        // ---- phase 1: fm 0-3 ----
        bf16x8 af[4], bgf[2], bof[2];
        #pragma unroll
        for (int i = 0; i < 4; ++i) af[i] = ldA(i, t);
        bgf[0] = ldG(0, t); bgf[1] = ldG(1, t);
        bof[0] = ldO(0, t); bof[1] = ldO(1, t);
        if (t + 2 < NK) stageA(t + 2);
        __builtin_amdgcn_s_barrier();
        asm volatile("s_waitcnt lgkmcnt(0)" ::: "memory");
        __builtin_amdgcn_sched_barrier(0);
        __builtin_amdgcn_s_setprio(1);
        #pragma unroll
        for (int fm = 0; fm < 4; ++fm)
            #pragma unroll
            for (int fn = 0; fn < 2; ++fn) {
                ag[fm][fn] = MFMA16(bgf[fn], af[fm], ag[fm][fn]);
                ao[fm][fn] = MFMA16(bof[fn], af[fm], ao[fm][fn]);
            }
        __builtin_amdgcn_s_setprio(0);
        __builtin_amdgcn_s_barrier();
        // ---- phase 2: fm 4-7 ----
        bf16x8 af2[4];
        #pragma unroll
        for (int i = 0; i < 4; ++i) af2[i] = ldA(4 + i, t);
        if (t + 2 < NK) {
            stageB(t + 2);
            asm volatile("s_waitcnt vmcnt(4)" ::: "memory");   // retire t+1's 4
        } else {
            asm volatile("s_waitcnt vmcnt(0)" ::: "memory");
        }
        __builtin_amdgcn_s_barrier();
        asm volatile("s_waitcnt lgkmcnt(0)" ::: "memory");
        __builtin_amdgcn_sched_barrier(0);
        __builtin_amdgcn_s_setprio(1);
        #pragma unroll
        for (int fm = 0; fm < 4; ++fm)
            #pragma unroll
            for (int fn = 0; fn < 2; ++fn) {
                ag[4+fm][fn] = MFMA16(bgf[fn], af2[fm], ag[4+fm][fn]);
                ao[4+fm][fn] = MFMA16(bof[fn], af2[fm], ao[4+fm][fn]);
            }
        __builtin_amdgcn_s_setprio(0);
        __builtin_amdgcn_s_barrier();
    }

    // epilogue: silu(g)*o, packed 8B bf16 stores (4 consecutive N cols/lane)
    u16* He = Hb + (size_t)e * GC * HDIM;
    int row0 = mt * 256 + wm * 128 + fr;
    int col0 = nt * 128 + wn * 32 + fg * 4;
    #pragma unroll
    for (int fm = 0; fm < 8; ++fm)
        #pragma unroll
        for (int fn = 0; fn < 2; ++fn) {
            s16x4 pk;
            #pragma unroll
            for (int r = 0; r < 4; ++r) {
                float gv = ag[fm][fn][r], ov = ao[fm][fn][r];
                float hv = gv / (1.f + __expf(-gv)) * ov;
                pk[r] = (short)f2bf(hv);
            }
            *(s16x4*)(He + (size_t)(row0 + fm * 16) * HDIM + col0 + fn * 16) = pk;
        }
}

// ======================================================================
// GEMM3 pipelined: BM=128 BN=256 BK=32, ring-4 LDS, counted vmcnt.
// EO = H * Wo^T, f32 out (16B stores).
// LDS: A 4x8KB @0, B 4x16KB @32768 = 96 KiB.
// ======================================================================
__global__ __launch_bounds__(512, 2) void gemm_out_v2(
        const u16* __restrict__ Hb, const u16* __restrict__ WoT,
        float* __restrict__ EO) {
    extern __shared__ char smem[];
    const int NK = HDIM / 32;                      // 128
    int bid = blockIdx.x;
    int swz = (bid & 7) * 80 + (bid >> 3);         // 640 % 8 == 0
    int nt = swz & 3, mt = (swz / 4) % 20, e = swz / 80;
    const char* A = (const char*)(Hb  + (size_t)e * GC * HDIM   + (size_t)mt * 128 * HDIM);
    const char* B = (const char*)(WoT + (size_t)e * MDIM * HDIM + (size_t)nt * 256 * HDIM);
    int tid = threadIdx.x, w = tid >> 6, l = tid & 63;
    int wm = w >> 2, wn = w & 3;
    int rl = l >> 2, cch = (l & 3) * 16;
    int fr = l & 15, fg = l >> 4;

    f32x4 acc[4][4];
    #pragma unroll
    for (int i = 0; i < 4; ++i)
        #pragma unroll
        for (int j = 0; j < 4; ++j) acc[i][j] = (f32x4){0,0,0,0};

    auto stageA = [&](int t) {                     // 1 load/thread
        int r = w * 16 + rl;
        gload16(A + ((size_t)r * HDIM + t * 32) * 2 + (cch ^ swzb(r)),
                smem + (t & 3) * 8192 + w * 1024);
    };
    auto stageB = [&](int t) {                     // 2 loads/thread
        char* dst = smem + 32768 + (t & 3) * 16384;
        #pragma unroll
        for (int i = 0; i < 2; ++i) {
            int r = (i * 8 + w) * 16 + rl;
            gload16(B + ((size_t)r * HDIM + t * 32) * 2 + (cch ^ swzb(r)),
                    dst + (i * 8 + w) * 1024);
        }
    };
    auto ldA = [&](int fm, int t) -> bf16x8 {
        int r = wm * 64 + fm * 16 + fr;
        return *(const bf16x8*)(smem + (t & 3) * 8192 + r * 64 + ((fg * 16) ^ swzb(r)));
    };
    auto ldB = [&](int fn, int t) -> bf16x8 {
        int r = wn * 64 + fn * 16 + fr;
        return *(const bf16x8*)(smem + 32768 + (t & 3) * 16384 + r * 64 + ((fg * 16) ^ swzb(r)));
    };

    stageA(0); stageB(0);
    stageA(1); stageB(1);
    asm volatile("s_waitcnt vmcnt(3)" ::: "memory");
    __builtin_amdgcn_s_barrier();

    #pragma unroll 1
    for (int t = 0; t < NK; ++t) {
        bf16x8 af[4], bf[4];
        #pragma unroll
        for (int i = 0; i < 4; ++i) { af[i] = ldA(i, t); bf[i] = ldB(i, t); }
        if (t + 2 < NK) {
            stageA(t + 2); stageB(t + 2);
            asm volatile("s_waitcnt vmcnt(3)" ::: "memory");
        } else {
            asm volatile("s_waitcnt vmcnt(0)" ::: "memory");
        }
        __builtin_amdgcn_s_barrier();
        asm volatile("s_waitcnt lgkmcnt(0)" ::: "memory");
        __builtin_amdgcn_sched_barrier(0);
        __builtin_amdgcn_s_setprio(1);
        #pragma unroll
        for (int fm = 0; fm < 4; ++fm)
            #pragma unroll
            for (int fn = 0; fn < 4; ++fn)
                acc[fm][fn] = MFMA16(bf[fn], af[fm], acc[fm][fn]);
        __builtin_amdgcn_s_setprio(0);
        __builtin_amdgcn_s_barrier();
    }

    float* Ee = EO + (size_t)e * GC * MDIM;
    int row0 = mt * 128 + wm * 64 + fr;
    int col0 = nt * 256 + wn * 64 + fg * 4;
    #pragma unroll
    for (int fm = 0; fm < 4; ++fm)
        #pragma unroll
        for (int fn = 0; fn < 4; ++fn)
            *(f32x4*)(Ee + (size_t)(row0 + fm * 16) * MDIM + col0 + fn * 16) = acc[fm][fn];
}

// ---------------- combine ----------------
__global__ __launch_bounds__(256) void combine_kernel(const float* __restrict__ EO,
                                                      const int* __restrict__ top_i,
                                                      const float* __restrict__ top_p,
                                                      const int* __restrict__ token_c,
                                                      float* __restrict__ out) {
    int tok = blockIdx.x, t = threadIdx.x;
    int g = tok >> 11;
    f32x4 acc = {0.f, 0.f, 0.f, 0.f};
    #pragma unroll
    for (int k = 0; k < 2; ++k) {
        int c = token_c[tok * 2 + k];
        if (c >= 0) {
            int e = top_i[tok * 2 + k];
            float p = top_p[tok * 2 + k];
            const float* src = EO + ((size_t)e * GC + g * CAP + c) * MDIM + t * 4;
            f32x4 v = *(const f32x4*)src;
            #pragma unroll
            for (int j = 0; j < 4; ++j) acc[j] += p * v[j];
        }
    }
    *(f32x4*)(out + (size_t)tok * MDIM + t * 4) = acc;
}

extern "C" void kernel_launch(void* const* d_in, const int* in_sizes, int n_in,
                              void* d_out, int out_size, void* d_ws, size_t ws_size,
                              hipStream_t stream) {
    (void)in_sizes; (void)n_in; (void)out_size; (void)ws_size;
    const float* inputs   = (const float*)d_in[0];
    const float* paddings = (const float*)d_in[1];
    const float* router_w = (const float*)d_in[2];
    const float* wi_gate  = (const float*)d_in[3];
    const float* wi_0     = (const float*)d_in[4];
    const float* wo       = (const float*)d_in[5];
    float* out = (float*)d_out;

    char* p = (char*)d_ws;
    u16* WgT = (u16*)p; p += (size_t)E * HDIM * MDIM * 2;
    u16* W0T = (u16*)p; p += (size_t)E * HDIM * MDIM * 2;
    u16* WoT = (u16*)p; p += (size_t)E * HDIM * MDIM * 2;
    u16* Xb  = (u16*)p; p += (size_t)E * GC * MDIM * 2;
    u16* Hb  = (u16*)p; p += (size_t)E * GC * HDIM * 2;
    float* EO = (float*)p; p += (size_t)E * GC * MDIM * 4;
    int*   top_i = (int*)p;   p += (size_t)G * S * TOPK * 4;
    float* top_p = (float*)p; p += (size_t)G * S * TOPK * 4;
    int*   token_c = (int*)p; p += (size_t)G * S * TOPK * 4;
    int*   slot_token = (int*)p; p += (size_t)E * G * CAP * 4;
    float* partials = (float*)p; p += (size_t)4096 * 17 * 4;
    float* sums = (float*)p; p += 4 * 17 * 4;

    hipMemsetAsync(token_c, 0xFF, (size_t)G * S * TOPK * 4, stream);
    hipMemsetAsync(slot_token, 0xFF, (size_t)E * G * CAP * 4, stream);

    hipFuncSetAttribute((const void*)gemm_ffn12_v2,
                        hipFuncAttributeMaxDynamicSharedMemorySize, 131072);
    hipFuncSetAttribute((const void*)gemm_out_v2,
                        hipFuncAttributeMaxDynamicSharedMemorySize, 98304);

    transpose_cvt<<<dim3(HDIM/32, MDIM/32, E), dim3(32, 8), 0, stream>>>(wi_gate, WgT, MDIM, HDIM);
    transpose_cvt<<<dim3(HDIM/32, MDIM/32, E), dim3(32, 8), 0, stream>>>(wi_0,   W0T, MDIM, HDIM);
    transpose_cvt<<<dim3(MDIM/32, HDIM/32, E), dim3(32, 8), 0, stream>>>(wo,     WoT, HDIM, MDIM);

    router_kernel<<<G * S / 4, 256, 0, stream>>>(inputs, router_w, top_i, top_p, partials);
    reduce_partials<<<G, 256, 0, stream>>>(partials, sums);
    scan_kernel<<<G * E, 256, 0, stream>>>(top_i, paddings, slot_token, token_c);
    gather_kernel<<<E * GC, 128, 0, stream>>>(inputs, slot_token, Xb);
    gemm_ffn12_v2<<<2560, 512, 131072, stream>>>(Xb, WgT, W0T, Hb);
    gemm_out_v2<<<640, 512, 98304, stream>>>(Hb, WoT, EO);
    combine_kernel<<<G * S, 256, 0, stream>>>(EO, top_i, top_p, token_c, out);
    aux_final<<<1, 1, 0, stream>>>(sums, out);
}

// Round 4
// 802.478 us; speedup vs baseline: 1.1254x; 1.0379x over previous
//
#include <hip/hip_runtime.h>
#include <hip/hip_bf16.h>
#include <math.h>

#define G 4
#define S 2048
#define MDIM 1024
#define E 8
#define HDIM 4096
#define TOPK 2
#define CAP 640
#define GC (G*CAP)      /* 2560 rows per expert */

typedef __attribute__((ext_vector_type(8))) short bf16x8;
typedef __attribute__((ext_vector_type(4))) short s16x4;
typedef __attribute__((ext_vector_type(4))) float f32x4;
typedef unsigned int u32;
typedef unsigned short u16;

#define MFMA16(a,b,c) __builtin_amdgcn_mfma_f32_16x16x32_bf16(a,b,c,0,0,0)

__device__ __forceinline__ u16 f2bf(float f) {
    union { float f; u32 u; } v; v.f = f;
    u32 r = v.u + 0x7fffu + ((v.u >> 16) & 1u);
    return (u16)(r >> 16);
}

__device__ __forceinline__ void gload16(const char* gp, char* lp) {
    __builtin_amdgcn_global_load_lds((const __attribute__((address_space(1))) u32*)gp,
                                     (__attribute__((address_space(3))) u32*)lp,
                                     16, 0, 0);
}

// swizzle for 64-byte LDS rows (XOR involution, both-sides applied)
__device__ __forceinline__ int swzb(int r) { return ((r >> 1) & 3) << 4; }

// ---------------- weight transpose + f32->bf16 convert (R2-proven 32x32) ----------------
// in: [E][R][C] f32   out: [E][C][R] bf16
__global__ __launch_bounds__(256) void transpose_cvt(const float* __restrict__ in,
                                                     u16* __restrict__ out, int R, int C) {
    int e = blockIdx.z;
    const float* ine = in + (size_t)e * R * C;
    u16* oute = out + (size_t)e * R * C;
    __shared__ float tile[32][33];
    int tx = threadIdx.x, ty = threadIdx.y;
    int x0 = blockIdx.x * 32, y0 = blockIdx.y * 32;
    #pragma unroll
    for (int i = 0; i < 4; ++i)
        tile[ty + i*8][tx] = ine[(size_t)(y0 + ty + i*8) * C + x0 + tx];
    __syncthreads();
    #pragma unroll
    for (int i = 0; i < 4; ++i)
        oute[(size_t)(x0 + ty + i*8) * R + y0 + tx] = f2bf(tile[tx][ty + i*8]);
}

// ---------------- router ----------------
__global__ __launch_bounds__(256) void router_kernel(const float* __restrict__ inp,
                                                     const float* __restrict__ rw,
                                                     int* __restrict__ top_i,
                                                     float* __restrict__ top_p,
                                                     float* __restrict__ partials) {
    int wid = threadIdx.x >> 6, lane = threadIdx.x & 63;
    int tok = blockIdx.x * 4 + wid;
    const float* x = inp + (size_t)tok * MDIM;
    float acc[E] = {0.f,0.f,0.f,0.f,0.f,0.f,0.f,0.f};
    #pragma unroll
    for (int rep = 0; rep < 4; ++rep) {
        int m0 = rep * 256 + lane * 4;
        f32x4 xv = *(const f32x4*)(x + m0);
        #pragma unroll
        for (int j = 0; j < 4; ++j) {
            const float* r = rw + (size_t)(m0 + j) * E;
            float xj = xv[j];
            #pragma unroll
            for (int e = 0; e < E; ++e) acc[e] += xj * r[e];
        }
    }
    #pragma unroll
    for (int e = 0; e < E; ++e)
        #pragma unroll
        for (int off = 32; off; off >>= 1) acc[e] += __shfl_down(acc[e], off);

    __shared__ float part[4][17];
    if (lane == 0) {
        float mx = acc[0];
        #pragma unroll
        for (int e = 1; e < E; ++e) mx = fmaxf(mx, acc[e]);
        float p[E], sum = 0.f;
        #pragma unroll
        for (int e = 0; e < E; ++e) { p[e] = expf(acc[e] - mx); sum += p[e]; }
        float inv = 1.f / sum;
        #pragma unroll
        for (int e = 0; e < E; ++e) p[e] *= inv;
        float lse = logf(sum) + mx;
        int i0 = 0;
        #pragma unroll
        for (int e = 1; e < E; ++e) if (acc[e] > acc[i0]) i0 = e;
        int i1 = (i0 == 0) ? 1 : 0;
        #pragma unroll
        for (int e = 0; e < E; ++e) if (e != i0 && acc[e] > acc[i1]) i1 = e;
        top_i[tok*2+0] = i0; top_i[tok*2+1] = i1;
        top_p[tok*2+0] = p[i0]; top_p[tok*2+1] = p[i1];
        #pragma unroll
        for (int e = 0; e < E; ++e) { part[wid][e] = p[e]; part[wid][8+e] = 0.f; }
        part[wid][8+i0] = 1.f; part[wid][8+i1] = 1.f;
        part[wid][16] = lse * lse;
    }
    __syncthreads();
    if (threadIdx.x < 17) {
        float v = part[0][threadIdx.x] + part[1][threadIdx.x] +
                  part[2][threadIdx.x] + part[3][threadIdx.x];
        partials[(size_t)blockIdx.x * 17 + threadIdx.x] = v;
    }
}

__global__ __launch_bounds__(256) void reduce_partials(const float* __restrict__ partials,
                                                       float* __restrict__ sums) {
    int g = blockIdx.x, t = threadIdx.x;
    float loc[17];
    #pragma unroll
    for (int c = 0; c < 17; ++c) loc[c] = 0.f;
    for (int r = t; r < 1024; r += 256) {
        const float* pr = partials + ((size_t)g * 1024 + r) * 17;
        #pragma unroll
        for (int c = 0; c < 17; ++c) loc[c] += pr[c];
    }
    __shared__ float red[256];
    for (int c = 0; c < 17; ++c) {
        red[t] = loc[c]; __syncthreads();
        for (int off = 128; off; off >>= 1) {
            if (t < off) red[t] += red[t + off];
            __syncthreads();
        }
        if (t == 0) sums[g * 17 + c] = red[0];
        __syncthreads();
    }
}

__global__ void aux_final(const float* __restrict__ sums, float* __restrict__ out) {
    float lb = 0.f, z = 0.f;
    for (int g = 0; g < G; ++g) {
        for (int e = 0; e < E; ++e)
            lb += (sums[g*17 + 8 + e] / (float)S) * (sums[g*17 + e] / (float)S);
        z += sums[g*17 + 16];
    }
    lb = lb / (float)(G * E) * (float)(E * E);
    z /= (float)(G * S);
    out[(size_t)G * S * MDIM] = 0.01f * lb + 0.001f * z;
}

// ---------------- capacity scan ----------------
__global__ __launch_bounds__(256) void scan_kernel(const int* __restrict__ top_i,
                                                   const float* __restrict__ pad,
                                                   int* __restrict__ slot_token,
                                                   int* __restrict__ token_c) {
    int b = blockIdx.x; int g = b >> 3, e = b & 7;
    int t = threadIdx.x;
    __shared__ int sums[256];
    int base = t * 16;
    int run = 0; unsigned mask16 = 0; int loc[16];
    #pragma unroll
    for (int j = 0; j < 16; ++j) {
        int i = base + j; int s = i >> 1, k = i & 1;
        int ex = top_i[((size_t)(g * S + s)) * 2 + k];
        int m = (ex == e) && (pad[g * S + s] == 0.f);
        run += m; loc[j] = run; mask16 |= ((unsigned)m << j);
    }
    sums[t] = run; __syncthreads();
    for (int off = 1; off < 256; off <<= 1) {
        int v = (t >= off) ? sums[t - off] : 0;
        __syncthreads();
        sums[t] += v;
        __syncthreads();
    }
    int excl = sums[t] - run;
    #pragma unroll
    for (int j = 0; j < 16; ++j) {
        if ((mask16 >> j) & 1u) {
            int pos = excl + loc[j];
            if (pos <= CAP) {
                int i = base + j; int s = i >> 1, k = i & 1;
                slot_token[((size_t)(e * G + g)) * CAP + (pos - 1)] = s;
                token_c[((size_t)(g * S + s)) * 2 + k] = pos - 1;
            }
        }
    }
}

// ---------------- gather tokens -> X bf16 [E][GC][MDIM] ----------------
__global__ __launch_bounds__(128) void gather_kernel(const float* __restrict__ inp,
                                                     const int* __restrict__ slot_token,
                                                     u16* __restrict__ X) {
    int row = blockIdx.x;
    int t = threadIdx.x;
    int s = slot_token[row];
    int g = (row % GC) / CAP;
    bf16x8 v;
    if (s >= 0) {
        const float* src = inp + ((size_t)(g * S + s)) * MDIM + t * 8;
        f32x4 a = *(const f32x4*)src;
        f32x4 b = *(const f32x4*)(src + 4);
        #pragma unroll
        for (int j = 0; j < 4; ++j) { v[j] = (short)f2bf(a[j]); v[4+j] = (short)f2bf(b[j]); }
    } else {
        #pragma unroll
        for (int j = 0; j < 8; ++j) v[j] = 0;
    }
    *(bf16x8*)(X + (size_t)row * MDIM + t * 8) = v;
}

// ======================================================================
// GEMM1+2 fused: BM=256 BN=128 BK=32, ring-4 LDS, 1 barrier/K-tile,
// counted vmcnt, hoisted addressing. NO reg-dbuf (keeps VGPR < cap so the
// counted vmcnt can't be broken by scratch spills).
// LDS: A 4x16KB @0, Bg 4x8KB @65536, B0 4x8KB @98304 = 128 KiB.
// ======================================================================
__global__ __launch_bounds__(512, 1) void gemm_ffn12_v4(
        const u16* __restrict__ Xb, const u16* __restrict__ WgT,
        const u16* __restrict__ W0T, u16* __restrict__ Hb) {
    extern __shared__ char smem[];
    const int NK = MDIM / 32;                      // 32
    int bid = blockIdx.x;
    int swz = (bid & 7) * 320 + (bid >> 3);        // bijective (2560 % 8 == 0)
    int mt = swz % 10, nt = (swz / 10) & 31, e = swz / 320;
    const char* A  = (const char*)(Xb  + (size_t)e * GC * MDIM   + (size_t)mt * 256 * MDIM);
    const char* Bg = (const char*)(WgT + (size_t)e * HDIM * MDIM + (size_t)nt * 128 * MDIM);
    const char* B0 = (const char*)(W0T + (size_t)e * HDIM * MDIM + (size_t)nt * 128 * MDIM);
    int tid = threadIdx.x, w = tid >> 6, l = tid & 63;
    int wm = w >> 2, wn = w & 3;                   // 2M x 4N waves
    int rl = l >> 2, cch = (l & 3) * 16;           // stage lane pieces
    int fr = l & 15, fg = l >> 4;                  // frag lane pieces
    int lswz = ((fr >> 1) & 3) << 4;               // lane-only read swizzle

    // hoisted per-lane global stage pointers (byte addrs at tile 0)
    int rA0 = (0 * 8 + w) * 16 + rl, rA1 = (1 * 8 + w) * 16 + rl, rB = w * 16 + rl;
    const char* gA0 = A  + (size_t)rA0 * MDIM * 2 + (cch ^ swzb(rA0));
    const char* gA1 = A  + (size_t)rA1 * MDIM * 2 + (cch ^ swzb(rA1));
    const char* gBg = Bg + (size_t)rB  * MDIM * 2 + (cch ^ swzb(rB));
    const char* gB0 = B0 + (size_t)rB  * MDIM * 2 + (cch ^ swzb(rB));
    // hoisted per-lane LDS read base offsets
    int baseA = (wm * 128 + fr) * 64 + ((fg * 16) ^ lswz);
    int baseB = (wn * 32  + fr) * 64 + ((fg * 16) ^ lswz);

    f32x4 ag[8][2], ao[8][2];
    #pragma unroll
    for (int i = 0; i < 8; ++i) {
        ag[i][0] = (f32x4){0,0,0,0}; ag[i][1] = (f32x4){0,0,0,0};
        ao[i][0] = (f32x4){0,0,0,0}; ao[i][1] = (f32x4){0,0,0,0};
    }

    auto stage = [&](int tt) {                     // 4 gloads for tile tt
        int kk = tt * 64, b = tt & 3;
        gload16(gA0 + kk, smem + b * 16384 + (0 * 8 + w) * 1024);
        gload16(gA1 + kk, smem + b * 16384 + (1 * 8 + w) * 1024);
        gload16(gBg + kk, smem + 65536 + b * 8192 + w * 1024);
        gload16(gB0 + kk, smem + 98304 + b * 8192 + w * 1024);
    };

    stage(0); stage(1);

    #pragma unroll 1
    for (int t = 0; t < NK; ++t) {
        if (t + 2 < NK) {
            stage(t + 2);
            asm volatile("s_waitcnt vmcnt(4)" ::: "memory");
        } else {
            asm volatile("s_waitcnt vmcnt(0)" ::: "memory");
        }
        __builtin_amdgcn_s_barrier();
        __builtin_amdgcn_sched_barrier(0);
        const char* bufA = smem + (t & 3) * 16384;
        const char* pG = smem + 65536 + (t & 3) * 8192 + baseB;
        const char* pO = smem + 98304 + (t & 3) * 8192 + baseB;
        bf16x8 bgf[2], bof[2], af[8];
        bgf[0] = *(const bf16x8*)(pG);  bgf[1] = *(const bf16x8*)(pG + 1024);
        bof[0] = *(const bf16x8*)(pO);  bof[1] = *(const bf16x8*)(pO + 1024);
        #pragma unroll
        for (int fm = 0; fm < 8; ++fm) af[fm] = *(const bf16x8*)(bufA + baseA + fm * 1024);
        __builtin_amdgcn_s_setprio(1);
        #pragma unroll
        for (int fm = 0; fm < 8; ++fm)
            #pragma unroll
            for (int fn = 0; fn < 2; ++fn) {
                ag[fm][fn] = MFMA16(bgf[fn], af[fm], ag[fm][fn]);
                ao[fm][fn] = MFMA16(bof[fn], af[fm], ao[fm][fn]);
            }
        __builtin_amdgcn_s_setprio(0);
    }

    // epilogue: silu(g)*o, packed 8B bf16 stores (4 consecutive N cols/lane)
    u16* He = Hb + (size_t)e * GC * HDIM;
    int row0 = mt * 256 + wm * 128 + fr;
    int col0 = nt * 128 + wn * 32 + fg * 4;
    #pragma unroll
    for (int fm = 0; fm < 8; ++fm)
        #pragma unroll
        for (int fn = 0; fn < 2; ++fn) {
            s16x4 pk;
            #pragma unroll
            for (int r = 0; r < 4; ++r) {
                float gv = ag[fm][fn][r], ov = ao[fm][fn][r];
                float hv = gv / (1.f + __expf(-gv)) * ov;
                pk[r] = (short)f2bf(hv);
            }
            *(s16x4*)(He + (size_t)(row0 + fm * 16) * HDIM + col0 + fn * 16) = pk;
        }
}

// ======================================================================
// GEMM3: BM=128 BN=256 BK=32, ring-4 LDS, 1 barrier/K-tile,
// reg-dbuf BOTH operands (est ~170 VGPR, spill-safe), counted vmcnt.
// LDS: A 4x8KB @0, B 4x16KB @32768 = 96 KiB.
// ======================================================================
__global__ __launch_bounds__(512, 1) void gemm_out_v4(
        const u16* __restrict__ Hb, const u16* __restrict__ WoT,
        float* __restrict__ EO) {
    extern __shared__ char smem[];
    const int NK = HDIM / 32;                      // 128
    int bid = blockIdx.x;
    int swz = (bid & 7) * 80 + (bid >> 3);         // bijective (640 % 8 == 0)
    int nt = swz & 3, mt = (swz / 4) % 20, e = swz / 80;
    const char* A = (const char*)(Hb  + (size_t)e * GC * HDIM   + (size_t)mt * 128 * HDIM);
    const char* B = (const char*)(WoT + (size_t)e * MDIM * HDIM + (size_t)nt * 256 * HDIM);
    int tid = threadIdx.x, w = tid >> 6, l = tid & 63;
    int wm = w >> 2, wn = w & 3;
    int rl = l >> 2, cch = (l & 3) * 16;
    int fr = l & 15, fg = l >> 4;
    int lswz = ((fr >> 1) & 3) << 4;

    int rA = w * 16 + rl, rB0 = (0 * 8 + w) * 16 + rl, rB1 = (1 * 8 + w) * 16 + rl;
    const char* gA  = A + (size_t)rA  * HDIM * 2 + (cch ^ swzb(rA));
    const char* gBa = B + (size_t)rB0 * HDIM * 2 + (cch ^ swzb(rB0));
    const char* gBb = B + (size_t)rB1 * HDIM * 2 + (cch ^ swzb(rB1));
    int baseA = (wm * 64 + fr) * 64 + ((fg * 16) ^ lswz);
    int baseB = (wn * 64 + fr) * 64 + ((fg * 16) ^ lswz);

    f32x4 acc[4][4];
    #pragma unroll
    for (int i = 0; i < 4; ++i)
        #pragma unroll
        for (int j = 0; j < 4; ++j) acc[i][j] = (f32x4){0,0,0,0};

    auto stage = [&](int tt) {                     // 3 gloads
        int kk = tt * 64, b = tt & 3;
        gload16(gA  + kk, smem + b * 8192 + w * 1024);
        gload16(gBa + kk, smem + 32768 + b * 16384 + (0 * 8 + w) * 1024);
        gload16(gBb + kk, smem + 32768 + b * 16384 + (1 * 8 + w) * 1024);
    };

    bf16x8 afA[4], bfA[4], afB[4], bfB[4];

    stage(0); stage(1);
    asm volatile("s_waitcnt vmcnt(3)" ::: "memory");
    __builtin_amdgcn_s_barrier();
    __builtin_amdgcn_sched_barrier(0);
    {
        const char* pA = smem + baseA;
        const char* pB = smem + 32768 + baseB;
        #pragma unroll
        for (int i = 0; i < 4; ++i) {
            afA[i] = *(const bf16x8*)(pA + i * 1024);
            bfA[i] = *(const bf16x8*)(pB + i * 1024);
        }
    }

    auto body = [&](int t, bf16x8 (&afc)[4], bf16x8 (&bfc)[4],
                    bf16x8 (&afn)[4], bf16x8 (&bfn)[4]) {
        if (t + 2 < NK) {
            stage(t + 2);
            asm volatile("s_waitcnt vmcnt(3)" ::: "memory");
        } else {
            asm volatile("s_waitcnt vmcnt(0)" ::: "memory");
        }
        __builtin_amdgcn_s_barrier();
        __builtin_amdgcn_sched_barrier(0);
        if (t + 1 < NK) {
            const char* pA = smem + ((t + 1) & 3) * 8192 + baseA;
            const char* pB = smem + 32768 + ((t + 1) & 3) * 16384 + baseB;
            #pragma unroll
            for (int i = 0; i < 4; ++i) {
                afn[i] = *(const bf16x8*)(pA + i * 1024);
                bfn[i] = *(const bf16x8*)(pB + i * 1024);
            }
        }
        __builtin_amdgcn_s_setprio(1);
        #pragma unroll
        for (int fm = 0; fm < 4; ++fm)
            #pragma unroll
            for (int fn = 0; fn < 4; ++fn)
                acc[fm][fn] = MFMA16(bfc[fn], afc[fm], acc[fm][fn]);
        __builtin_amdgcn_s_setprio(0);
    };

    #pragma unroll 1
    for (int t = 0; t < NK; t += 2) {
        body(t, afA, bfA, afB, bfB);
        body(t + 1, afB, bfB, afA, bfA);
    }

    float* Ee = EO + (size_t)e * GC * MDIM;
    int row0 = mt * 128 + wm * 64 + fr;
    int col0 = nt * 256 + wn * 64 + fg * 4;
    #pragma unroll
    for (int fm = 0; fm < 4; ++fm)
        #pragma unroll
        for (int fn = 0; fn < 4; ++fn)
            *(f32x4*)(Ee + (size_t)(row0 + fm * 16) * MDIM + col0 + fn * 16) = acc[fm][fn];
}

// ---------------- combine ----------------
__global__ __launch_bounds__(256) void combine_kernel(const float* __restrict__ EO,
                                                      const int* __restrict__ top_i,
                                                      const float* __restrict__ top_p,
                                                      const int* __restrict__ token_c,
                                                      float* __restrict__ out) {
    int tok = blockIdx.x, t = threadIdx.x;
    int g = tok >> 11;
    f32x4 acc = {0.f, 0.f, 0.f, 0.f};
    #pragma unroll
    for (int k = 0; k < 2; ++k) {
        int c = token_c[tok * 2 + k];
        if (c >= 0) {
            int e = top_i[tok * 2 + k];
            float p = top_p[tok * 2 + k];
            const float* src = EO + ((size_t)e * GC + g * CAP + c) * MDIM + t * 4;
            f32x4 v = *(const f32x4*)src;
            #pragma unroll
            for (int j = 0; j < 4; ++j) acc[j] += p * v[j];
        }
    }
    *(f32x4*)(out + (size_t)tok * MDIM + t * 4) = acc;
}

extern "C" void kernel_launch(void* const* d_in, const int* in_sizes, int n_in,
                              void* d_out, int out_size, void* d_ws, size_t ws_size,
                              hipStream_t stream) {
    (void)in_sizes; (void)n_in; (void)out_size; (void)ws_size;
    const float* inputs   = (const float*)d_in[0];
    const float* paddings = (const float*)d_in[1];
    const float* router_w = (const float*)d_in[2];
    const float* wi_gate  = (const float*)d_in[3];
    const float* wi_0     = (const float*)d_in[4];
    const float* wo       = (const float*)d_in[5];
    float* out = (float*)d_out;

    char* p = (char*)d_ws;
    u16* WgT = (u16*)p; p += (size_t)E * HDIM * MDIM * 2;
    u16* W0T = (u16*)p; p += (size_t)E * HDIM * MDIM * 2;
    u16* WoT = (u16*)p; p += (size_t)E * HDIM * MDIM * 2;
    u16* Xb  = (u16*)p; p += (size_t)E * GC * MDIM * 2;
    u16* Hb  = (u16*)p; p += (size_t)E * GC * HDIM * 2;
    float* EO = (float*)p; p += (size_t)E * GC * MDIM * 4;
    int*   top_i = (int*)p;   p += (size_t)G * S * TOPK * 4;
    float* top_p = (float*)p; p += (size_t)G * S * TOPK * 4;
    int*   token_c = (int*)p; p += (size_t)G * S * TOPK * 4;
    int*   slot_token = (int*)p; p += (size_t)E * G * CAP * 4;
    float* partials = (float*)p; p += (size_t)4096 * 17 * 4;
    float* sums = (float*)p; p += 4 * 17 * 4;

    hipMemsetAsync(token_c, 0xFF, (size_t)G * S * TOPK * 4, stream);
    hipMemsetAsync(slot_token, 0xFF, (size_t)E * G * CAP * 4, stream);

    hipFuncSetAttribute((const void*)gemm_ffn12_v4,
                        hipFuncAttributeMaxDynamicSharedMemorySize, 131072);
    hipFuncSetAttribute((const void*)gemm_out_v4,
                        hipFuncAttributeMaxDynamicSharedMemorySize, 98304);

    transpose_cvt<<<dim3(HDIM/32, MDIM/32, E), dim3(32, 8), 0, stream>>>(wi_gate, WgT, MDIM, HDIM);
    transpose_cvt<<<dim3(HDIM/32, MDIM/32, E), dim3(32, 8), 0, stream>>>(wi_0,   W0T, MDIM, HDIM);
    transpose_cvt<<<dim3(MDIM/32, HDIM/32, E), dim3(32, 8), 0, stream>>>(wo,     WoT, HDIM, MDIM);

    router_kernel<<<G * S / 4, 256, 0, stream>>>(inputs, router_w, top_i, top_p, partials);
    reduce_partials<<<G, 256, 0, stream>>>(partials, sums);
    scan_kernel<<<G * E, 256, 0, stream>>>(top_i, paddings, slot_token, token_c);
    gather_kernel<<<E * GC, 128, 0, stream>>>(inputs, slot_token, Xb);
    gemm_ffn12_v4<<<2560, 512, 131072, stream>>>(Xb, WgT, W0T, Hb);
    gemm_out_v4<<<640, 512, 98304, stream>>>(Hb, WoT, EO);
    combine_kernel<<<G * S, 256, 0, stream>>>(EO, top_i, top_p, token_c, out);
    aux_final<<<1, 1, 0, stream>>>(sums, out);
}

// Round 5
// 796.810 us; speedup vs baseline: 1.1334x; 1.0071x over previous
//
#include <hip/hip_runtime.h>
#include <hip/hip_bf16.h>
#include <math.h>

#define G 4
#define S 2048
#define MDIM 1024
#define E 8
#define HDIM 4096
#define TOPK 2
#define CAP 640
#define GC (G*CAP)      /* 2560 rows per expert */

typedef __attribute__((ext_vector_type(8))) short bf16x8;
typedef __attribute__((ext_vector_type(4))) short s16x4;
typedef __attribute__((ext_vector_type(4))) float f32x4;
typedef unsigned int u32;
typedef unsigned short u16;

#define MFMA16(a,b,c) __builtin_amdgcn_mfma_f32_16x16x32_bf16(a,b,c,0,0,0)

__device__ __forceinline__ u16 f2bf(float f) {
    union { float f; u32 u; } v; v.f = f;
    u32 r = v.u + 0x7fffu + ((v.u >> 16) & 1u);
    return (u16)(r >> 16);
}

__device__ __forceinline__ void gload16(const char* gp, char* lp) {
    __builtin_amdgcn_global_load_lds((const __attribute__((address_space(1))) u32*)gp,
                                     (__attribute__((address_space(3))) u32*)lp,
                                     16, 0, 0);
}

// swizzle for 64-byte LDS rows (XOR involution, both-sides applied)
__device__ __forceinline__ int swzb(int r) { return ((r >> 1) & 3) << 4; }

// ---------------- weight transpose + f32->bf16 convert (64x64, vector both ways) ----
// in: [E][R][C] f32   out: [E][C][R] bf16.  tile[a][b] = in[y0+a][x0+b];
// out[x0+cc][y0+rr] = tile[rr][cc]  (axis re-derived; R3's bug was tile[cc][rr])
__global__ __launch_bounds__(256) void transpose_cvt(const float* __restrict__ in,
                                                     u16* __restrict__ out, int R, int C) {
    int e = blockIdx.z;
    const float* ine = in + (size_t)e * R * C;
    u16* oute = out + (size_t)e * R * C;
    __shared__ float tile[64][68];
    int t = threadIdx.x;
    int x0 = blockIdx.x * 64, y0 = blockIdx.y * 64;
    int lx = (t & 15) * 4, ly = t >> 4;            // load: f32x4, 16 rows/pass
    #pragma unroll
    for (int i = 0; i < 4; ++i) {
        f32x4 v = *(const f32x4*)(ine + (size_t)(y0 + ly + i * 16) * C + x0 + lx);
        *(f32x4*)&tile[ly + i * 16][lx] = v;
    }
    __syncthreads();
    int rr0 = (t & 15) * 4, cb = t >> 4;           // store: lanes 0-15 sweep rr -> 128B/16 lanes
    #pragma unroll
    for (int p = 0; p < 4; ++p) {
        int cc = cb + p * 16;
        s16x4 pk;
        #pragma unroll
        for (int j = 0; j < 4; ++j) pk[j] = (short)f2bf(tile[rr0 + j][cc]);
        *(s16x4*)(oute + (size_t)(x0 + cc) * R + y0 + rr0) = pk;
    }
}

// ---------------- router ----------------
__global__ __launch_bounds__(256) void router_kernel(const float* __restrict__ inp,
                                                     const float* __restrict__ rw,
                                                     int* __restrict__ top_i,
                                                     float* __restrict__ top_p,
                                                     float* __restrict__ partials) {
    int wid = threadIdx.x >> 6, lane = threadIdx.x & 63;
    int tok = blockIdx.x * 4 + wid;
    const float* x = inp + (size_t)tok * MDIM;
    float acc[E] = {0.f,0.f,0.f,0.f,0.f,0.f,0.f,0.f};
    #pragma unroll
    for (int rep = 0; rep < 4; ++rep) {
        int m0 = rep * 256 + lane * 4;
        f32x4 xv = *(const f32x4*)(x + m0);
        #pragma unroll
        for (int j = 0; j < 4; ++j) {
            const float* r = rw + (size_t)(m0 + j) * E;
            float xj = xv[j];
            #pragma unroll
            for (int e = 0; e < E; ++e) acc[e] += xj * r[e];
        }
    }
    #pragma unroll
    for (int e = 0; e < E; ++e)
        #pragma unroll
        for (int off = 32; off; off >>= 1) acc[e] += __shfl_down(acc[e], off);

    __shared__ float part[4][17];
    if (lane == 0) {
        float mx = acc[0];
        #pragma unroll
        for (int e = 1; e < E; ++e) mx = fmaxf(mx, acc[e]);
        float p[E], sum = 0.f;
        #pragma unroll
        for (int e = 0; e < E; ++e) { p[e] = expf(acc[e] - mx); sum += p[e]; }
        float inv = 1.f / sum;
        #pragma unroll
        for (int e = 0; e < E; ++e) p[e] *= inv;
        float lse = logf(sum) + mx;
        int i0 = 0;
        #pragma unroll
        for (int e = 1; e < E; ++e) if (acc[e] > acc[i0]) i0 = e;
        int i1 = (i0 == 0) ? 1 : 0;
        #pragma unroll
        for (int e = 0; e < E; ++e) if (e != i0 && acc[e] > acc[i1]) i1 = e;
        top_i[tok*2+0] = i0; top_i[tok*2+1] = i1;
        top_p[tok*2+0] = p[i0]; top_p[tok*2+1] = p[i1];
        #pragma unroll
        for (int e = 0; e < E; ++e) { part[wid][e] = p[e]; part[wid][8+e] = 0.f; }
        part[wid][8+i0] = 1.f; part[wid][8+i1] = 1.f;
        part[wid][16] = lse * lse;
    }
    __syncthreads();
    if (threadIdx.x < 17) {
        float v = part[0][threadIdx.x] + part[1][threadIdx.x] +
                  part[2][threadIdx.x] + part[3][threadIdx.x];
        partials[(size_t)blockIdx.x * 17 + threadIdx.x] = v;
    }
}

__global__ __launch_bounds__(256) void reduce_partials(const float* __restrict__ partials,
                                                       float* __restrict__ sums) {
    int g = blockIdx.x, t = threadIdx.x;
    float loc[17];
    #pragma unroll
    for (int c = 0; c < 17; ++c) loc[c] = 0.f;
    for (int r = t; r < 1024; r += 256) {
        const float* pr = partials + ((size_t)g * 1024 + r) * 17;
        #pragma unroll
        for (int c = 0; c < 17; ++c) loc[c] += pr[c];
    }
    __shared__ float red[256];
    for (int c = 0; c < 17; ++c) {
        red[t] = loc[c]; __syncthreads();
        for (int off = 128; off; off >>= 1) {
            if (t < off) red[t] += red[t + off];
            __syncthreads();
        }
        if (t == 0) sums[g * 17 + c] = red[0];
        __syncthreads();
    }
}

__global__ void aux_final(const float* __restrict__ sums, float* __restrict__ out) {
    float lb = 0.f, z = 0.f;
    for (int g = 0; g < G; ++g) {
        for (int e = 0; e < E; ++e)
            lb += (sums[g*17 + 8 + e] / (float)S) * (sums[g*17 + e] / (float)S);
        z += sums[g*17 + 16];
    }
    lb = lb / (float)(G * E) * (float)(E * E);
    z /= (float)(G * S);
    out[(size_t)G * S * MDIM] = 0.01f * lb + 0.001f * z;
}

// ---------------- capacity scan ----------------
__global__ __launch_bounds__(256) void scan_kernel(const int* __restrict__ top_i,
                                                   const float* __restrict__ pad,
                                                   int* __restrict__ slot_token,
                                                   int* __restrict__ token_c) {
    int b = blockIdx.x; int g = b >> 3, e = b & 7;
    int t = threadIdx.x;
    __shared__ int sums[256];
    int base = t * 16;
    int run = 0; unsigned mask16 = 0; int loc[16];
    #pragma unroll
    for (int j = 0; j < 16; ++j) {
        int i = base + j; int s = i >> 1, k = i & 1;
        int ex = top_i[((size_t)(g * S + s)) * 2 + k];
        int m = (ex == e) && (pad[g * S + s] == 0.f);
        run += m; loc[j] = run; mask16 |= ((unsigned)m << j);
    }
    sums[t] = run; __syncthreads();
    for (int off = 1; off < 256; off <<= 1) {
        int v = (t >= off) ? sums[t - off] : 0;
        __syncthreads();
        sums[t] += v;
        __syncthreads();
    }
    int excl = sums[t] - run;
    #pragma unroll
    for (int j = 0; j < 16; ++j) {
        if ((mask16 >> j) & 1u) {
            int pos = excl + loc[j];
            if (pos <= CAP) {
                int i = base + j; int s = i >> 1, k = i & 1;
                slot_token[((size_t)(e * G + g)) * CAP + (pos - 1)] = s;
                token_c[((size_t)(g * S + s)) * 2 + k] = pos - 1;
            }
        }
    }
}

// ---------------- gather tokens -> X bf16 [E][GC][MDIM] ----------------
__global__ __launch_bounds__(128) void gather_kernel(const float* __restrict__ inp,
                                                     const int* __restrict__ slot_token,
                                                     u16* __restrict__ X) {
    int row = blockIdx.x;
    int t = threadIdx.x;
    int s = slot_token[row];
    int g = (row % GC) / CAP;
    bf16x8 v;
    if (s >= 0) {
        const float* src = inp + ((size_t)(g * S + s)) * MDIM + t * 8;
        f32x4 a = *(const f32x4*)src;
        f32x4 b = *(const f32x4*)(src + 4);
        #pragma unroll
        for (int j = 0; j < 4; ++j) { v[j] = (short)f2bf(a[j]); v[4+j] = (short)f2bf(b[j]); }
    } else {
        #pragma unroll
        for (int j = 0; j < 8; ++j) v[j] = 0;
    }
    *(bf16x8*)(X + (size_t)row * MDIM + t * 8) = v;
}

// ======================================================================
// GEMM1+2 fused: BM=256 BN=128 BK=32, ring-4 LDS, 1 barrier/K-tile,
// counted vmcnt, hoisted addressing, af_lo reg-dbuf (+16 VGPR, stays
// under the 256-total 2-wave/SIMD cliff; acc lives in AGPR).
// Overlap: batch1 MFMAs (fm0-3, in-reg A) run while af_hi + af_lo(t+1)
// ds_reads drain on the LDS pipe.
// LDS: A 4x16KB @0, Bg 4x8KB @65536, B0 4x8KB @98304 = 128 KiB.
// ======================================================================
__global__ __launch_bounds__(512, 1) void gemm_ffn12_v5(
        const u16* __restrict__ Xb, const u16* __restrict__ WgT,
        const u16* __restrict__ W0T, u16* __restrict__ Hb) {
    extern __shared__ char smem[];
    const int NK = MDIM / 32;                      // 32
    int bid = blockIdx.x;
    int swz = (bid & 7) * 320 + (bid >> 3);        // bijective (2560 % 8 == 0)
    int mt = swz % 10, nt = (swz / 10) & 31, e = swz / 320;
    const char* A  = (const char*)(Xb  + (size_t)e * GC * MDIM   + (size_t)mt * 256 * MDIM);
    const char* Bg = (const char*)(WgT + (size_t)e * HDIM * MDIM + (size_t)nt * 128 * MDIM);
    const char* B0 = (const char*)(W0T + (size_t)e * HDIM * MDIM + (size_t)nt * 128 * MDIM);
    int tid = threadIdx.x, w = tid >> 6, l = tid & 63;
    int wm = w >> 2, wn = w & 3;                   // 2M x 4N waves
    int rl = l >> 2, cch = (l & 3) * 16;           // stage lane pieces
    int fr = l & 15, fg = l >> 4;                  // frag lane pieces
    int lswz = ((fr >> 1) & 3) << 4;               // lane-only read swizzle

    int rA0 = (0 * 8 + w) * 16 + rl, rA1 = (1 * 8 + w) * 16 + rl, rB = w * 16 + rl;
    const char* gA0 = A  + (size_t)rA0 * MDIM * 2 + (cch ^ swzb(rA0));
    const char* gA1 = A  + (size_t)rA1 * MDIM * 2 + (cch ^ swzb(rA1));
    const char* gBg = Bg + (size_t)rB  * MDIM * 2 + (cch ^ swzb(rB));
    const char* gB0 = B0 + (size_t)rB  * MDIM * 2 + (cch ^ swzb(rB));
    int baseA = (wm * 128 + fr) * 64 + ((fg * 16) ^ lswz);
    int baseB = (wn * 32  + fr) * 64 + ((fg * 16) ^ lswz);

    f32x4 ag[8][2], ao[8][2];
    #pragma unroll
    for (int i = 0; i < 8; ++i) {
        ag[i][0] = (f32x4){0,0,0,0}; ag[i][1] = (f32x4){0,0,0,0};
        ao[i][0] = (f32x4){0,0,0,0}; ao[i][1] = (f32x4){0,0,0,0};
    }

    auto stage = [&](int tt) {                     // 4 gloads for tile tt
        int kk = tt * 64, b = tt & 3;
        gload16(gA0 + kk, smem + b * 16384 + (0 * 8 + w) * 1024);
        gload16(gA1 + kk, smem + b * 16384 + (1 * 8 + w) * 1024);
        gload16(gBg + kk, smem + 65536 + b * 8192 + w * 1024);
        gload16(gB0 + kk, smem + 98304 + b * 8192 + w * 1024);
    };

    bf16x8 afL0[4], afL1[4];

    // prologue: stage 0,1; retire 0; preload af_lo(0)
    stage(0); stage(1);
    asm volatile("s_waitcnt vmcnt(4)" ::: "memory");
    __builtin_amdgcn_s_barrier();
    __builtin_amdgcn_sched_barrier(0);
    {
        const char* p0 = smem + baseA;
        #pragma unroll
        for (int i = 0; i < 4; ++i) afL0[i] = *(const bf16x8*)(p0 + i * 1024);
    }

    auto body = [&](int t, bf16x8 (&loC)[4], bf16x8 (&loN)[4]) {
        if (t + 2 < NK) {
            stage(t + 2);
            asm volatile("s_waitcnt vmcnt(4)" ::: "memory");
        } else {
            asm volatile("s_waitcnt vmcnt(0)" ::: "memory");
        }
        __builtin_amdgcn_s_barrier();
        __builtin_amdgcn_sched_barrier(0);
        // issue order: B(t) first (first consumed), then af_hi(t), then af_lo(t+1)
        const char* pG = smem + 65536 + (t & 3) * 8192 + baseB;
        const char* pO = smem + 98304 + (t & 3) * 8192 + baseB;
        bf16x8 bgf[2], bof[2], hi[4];
        bgf[0] = *(const bf16x8*)(pG);  bgf[1] = *(const bf16x8*)(pG + 1024);
        bof[0] = *(const bf16x8*)(pO);  bof[1] = *(const bf16x8*)(pO + 1024);
        const char* bufA = smem + (t & 3) * 16384 + baseA;
        #pragma unroll
        for (int i = 0; i < 4; ++i) hi[i] = *(const bf16x8*)(bufA + (4 + i) * 1024);
        if (t + 1 < NK) {
            const char* bufN = smem + ((t + 1) & 3) * 16384 + baseA;
            #pragma unroll
            for (int i = 0; i < 4; ++i) loN[i] = *(const bf16x8*)(bufN + i * 1024);
        }
        __builtin_amdgcn_s_setprio(1);
        #pragma unroll
        for (int fm = 0; fm < 4; ++fm)
            #pragma unroll
            for (int fn = 0; fn < 2; ++fn) {
                ag[fm][fn] = MFMA16(bgf[fn], loC[fm], ag[fm][fn]);
                ao[fm][fn] = MFMA16(bof[fn], loC[fm], ao[fm][fn]);
            }
        #pragma unroll
        for (int fm = 0; fm < 4; ++fm)
            #pragma unroll
            for (int fn = 0; fn < 2; ++fn) {
                ag[4+fm][fn] = MFMA16(bgf[fn], hi[fm], ag[4+fm][fn]);
                ao[4+fm][fn] = MFMA16(bof[fn], hi[fm], ao[4+fm][fn]);
            }
        __builtin_amdgcn_s_setprio(0);
    };

    #pragma unroll 1
    for (int t = 0; t < NK; t += 2) {
        body(t, afL0, afL1);
        body(t + 1, afL1, afL0);
    }

    // epilogue: silu(g)*o, packed 8B bf16 stores (4 consecutive N cols/lane)
    u16* He = Hb + (size_t)e * GC * HDIM;
    int row0 = mt * 256 + wm * 128 + fr;
    int col0 = nt * 128 + wn * 32 + fg * 4;
    #pragma unroll
    for (int fm = 0; fm < 8; ++fm)
        #pragma unroll
        for (int fn = 0; fn < 2; ++fn) {
            s16x4 pk;
            #pragma unroll
            for (int r = 0; r < 4; ++r) {
                float gv = ag[fm][fn][r], ov = ao[fm][fn][r];
                float hv = gv / (1.f + __expf(-gv)) * ov;
                pk[r] = (short)f2bf(hv);
            }
            *(s16x4*)(He + (size_t)(row0 + fm * 16) * HDIM + col0 + fn * 16) = pk;
        }
}

// ======================================================================
// GEMM3: BM=128 BN=256 BK=32, ring-4 LDS, 1 barrier/K-tile,
// reg-dbuf BOTH operands (proven in R4), counted vmcnt.
// LDS: A 4x8KB @0, B 4x16KB @32768 = 96 KiB.
// ======================================================================
__global__ __launch_bounds__(512, 1) void gemm_out_v4(
        const u16* __restrict__ Hb, const u16* __restrict__ WoT,
        float* __restrict__ EO) {
    extern __shared__ char smem[];
    const int NK = HDIM / 32;                      // 128
    int bid = blockIdx.x;
    int swz = (bid & 7) * 80 + (bid >> 3);         // bijective (640 % 8 == 0)
    int nt = swz & 3, mt = (swz / 4) % 20, e = swz / 80;
    const char* A = (const char*)(Hb  + (size_t)e * GC * HDIM   + (size_t)mt * 128 * HDIM);
    const char* B = (const char*)(WoT + (size_t)e * MDIM * HDIM + (size_t)nt * 256 * HDIM);
    int tid = threadIdx.x, w = tid >> 6, l = tid & 63;
    int wm = w >> 2, wn = w & 3;
    int rl = l >> 2, cch = (l & 3) * 16;
    int fr = l & 15, fg = l >> 4;
    int lswz = ((fr >> 1) & 3) << 4;

    int rA = w * 16 + rl, rB0 = (0 * 8 + w) * 16 + rl, rB1 = (1 * 8 + w) * 16 + rl;
    const char* gA  = A + (size_t)rA  * HDIM * 2 + (cch ^ swzb(rA));
    const char* gBa = B + (size_t)rB0 * HDIM * 2 + (cch ^ swzb(rB0));
    const char* gBb = B + (size_t)rB1 * HDIM * 2 + (cch ^ swzb(rB1));
    int baseA = (wm * 64 + fr) * 64 + ((fg * 16) ^ lswz);
    int baseB = (wn * 64 + fr) * 64 + ((fg * 16) ^ lswz);

    f32x4 acc[4][4];
    #pragma unroll
    for (int i = 0; i < 4; ++i)
        #pragma unroll
        for (int j = 0; j < 4; ++j) acc[i][j] = (f32x4){0,0,0,0};

    auto stage = [&](int tt) {                     // 3 gloads
        int kk = tt * 64, b = tt & 3;
        gload16(gA  + kk, smem + b * 8192 + w * 1024);
        gload16(gBa + kk, smem + 32768 + b * 16384 + (0 * 8 + w) * 1024);
        gload16(gBb + kk, smem + 32768 + b * 16384 + (1 * 8 + w) * 1024);
    };

    bf16x8 afA[4], bfA[4], afB[4], bfB[4];

    stage(0); stage(1);
    asm volatile("s_waitcnt vmcnt(3)" ::: "memory");
    __builtin_amdgcn_s_barrier();
    __builtin_amdgcn_sched_barrier(0);
    {
        const char* pA = smem + baseA;
        const char* pB = smem + 32768 + baseB;
        #pragma unroll
        for (int i = 0; i < 4; ++i) {
            afA[i] = *(const bf16x8*)(pA + i * 1024);
            bfA[i] = *(const bf16x8*)(pB + i * 1024);
        }
    }

    auto body = [&](int t, bf16x8 (&afc)[4], bf16x8 (&bfc)[4],
                    bf16x8 (&afn)[4], bf16x8 (&bfn)[4]) {
        if (t + 2 < NK) {
            stage(t + 2);
            asm volatile("s_waitcnt vmcnt(3)" ::: "memory");
        } else {
            asm volatile("s_waitcnt vmcnt(0)" ::: "memory");
        }
        __builtin_amdgcn_s_barrier();
        __builtin_amdgcn_sched_barrier(0);
        if (t + 1 < NK) {
            const char* pA = smem + ((t + 1) & 3) * 8192 + baseA;
            const char* pB = smem + 32768 + ((t + 1) & 3) * 16384 + baseB;
            #pragma unroll
            for (int i = 0; i < 4; ++i) {
                afn[i] = *(const bf16x8*)(pA + i * 1024);
                bfn[i] = *(const bf16x8*)(pB + i * 1024);
            }
        }
        __builtin_amdgcn_s_setprio(1);
        #pragma unroll
        for (int fm = 0; fm < 4; ++fm)
            #pragma unroll
            for (int fn = 0; fn < 4; ++fn)
                acc[fm][fn] = MFMA16(bfc[fn], afc[fm], acc[fm][fn]);
        __builtin_amdgcn_s_setprio(0);
    };

    #pragma unroll 1
    for (int t = 0; t < NK; t += 2) {
        body(t, afA, bfA, afB, bfB);
        body(t + 1, afB, bfB, afA, bfA);
    }

    float* Ee = EO + (size_t)e * GC * MDIM;
    int row0 = mt * 128 + wm * 64 + fr;
    int col0 = nt * 256 + wn * 64 + fg * 4;
    #pragma unroll
    for (int fm = 0; fm < 4; ++fm)
        #pragma unroll
        for (int fn = 0; fn < 4; ++fn)
            *(f32x4*)(Ee + (size_t)(row0 + fm * 16) * MDIM + col0 + fn * 16) = acc[fm][fn];
}

// ---------------- combine ----------------
__global__ __launch_bounds__(256) void combine_kernel(const float* __restrict__ EO,
                                                      const int* __restrict__ top_i,
                                                      const float* __restrict__ top_p,
                                                      const int* __restrict__ token_c,
                                                      float* __restrict__ out) {
    int tok = blockIdx.x, t = threadIdx.x;
    int g = tok >> 11;
    f32x4 acc = {0.f, 0.f, 0.f, 0.f};
    #pragma unroll
    for (int k = 0; k < 2; ++k) {
        int c = token_c[tok * 2 + k];
        if (c >= 0) {
            int e = top_i[tok * 2 + k];
            float p = top_p[tok * 2 + k];
            const float* src = EO + ((size_t)e * GC + g * CAP + c) * MDIM + t * 4;
            f32x4 v = *(const f32x4*)src;
            #pragma unroll
            for (int j = 0; j < 4; ++j) acc[j] += p * v[j];
        }
    }
    *(f32x4*)(out + (size_t)tok * MDIM + t * 4) = acc;
}

extern "C" void kernel_launch(void* const* d_in, const int* in_sizes, int n_in,
                              void* d_out, int out_size, void* d_ws, size_t ws_size,
                              hipStream_t stream) {
    (void)in_sizes; (void)n_in; (void)out_size; (void)ws_size;
    const float* inputs   = (const float*)d_in[0];
    const float* paddings = (const float*)d_in[1];
    const float* router_w = (const float*)d_in[2];
    const float* wi_gate  = (const float*)d_in[3];
    const float* wi_0     = (const float*)d_in[4];
    const float* wo       = (const float*)d_in[5];
    float* out = (float*)d_out;

    char* p = (char*)d_ws;
    u16* WgT = (u16*)p; p += (size_t)E * HDIM * MDIM * 2;
    u16* W0T = (u16*)p; p += (size_t)E * HDIM * MDIM * 2;
    u16* WoT = (u16*)p; p += (size_t)E * HDIM * MDIM * 2;
    u16* Xb  = (u16*)p; p += (size_t)E * GC * MDIM * 2;
    u16* Hb  = (u16*)p; p += (size_t)E * GC * HDIM * 2;
    float* EO = (float*)p; p += (size_t)E * GC * MDIM * 4;
    int*   top_i = (int*)p;   p += (size_t)G * S * TOPK * 4;
    float* top_p = (float*)p; p += (size_t)G * S * TOPK * 4;
    int*   token_c = (int*)p; p += (size_t)G * S * TOPK * 4;
    int*   slot_token = (int*)p; p += (size_t)E * G * CAP * 4;
    float* partials = (float*)p; p += (size_t)4096 * 17 * 4;
    float* sums = (float*)p; p += 4 * 17 * 4;

    hipMemsetAsync(token_c, 0xFF, (size_t)G * S * TOPK * 4, stream);
    hipMemsetAsync(slot_token, 0xFF, (size_t)E * G * CAP * 4, stream);

    hipFuncSetAttribute((const void*)gemm_ffn12_v5,
                        hipFuncAttributeMaxDynamicSharedMemorySize, 131072);
    hipFuncSetAttribute((const void*)gemm_out_v4,
                        hipFuncAttributeMaxDynamicSharedMemorySize, 98304);

    transpose_cvt<<<dim3(HDIM/64, MDIM/64, E), 256, 0, stream>>>(wi_gate, WgT, MDIM, HDIM);
    transpose_cvt<<<dim3(HDIM/64, MDIM/64, E), 256, 0, stream>>>(wi_0,   W0T, MDIM, HDIM);
    transpose_cvt<<<dim3(MDIM/64, HDIM/64, E), 256, 0, stream>>>(wo,     WoT, HDIM, MDIM);

    router_kernel<<<G * S / 4, 256, 0, stream>>>(inputs, router_w, top_i, top_p, partials);
    reduce_partials<<<G, 256, 0, stream>>>(partials, sums);
    scan_kernel<<<G * E, 256, 0, stream>>>(top_i, paddings, slot_token, token_c);
    gather_kernel<<<E * GC, 128, 0, stream>>>(inputs, slot_token, Xb);
    gemm_ffn12_v5<<<2560, 512, 131072, stream>>>(Xb, WgT, W0T, Hb);
    gemm_out_v4<<<640, 512, 98304, stream>>>(Hb, WoT, EO);
    combine_kernel<<<G * S, 256, 0, stream>>>(EO, top_i, top_p, token_c, out);
    aux_final<<<1, 1, 0, stream>>>(sums, out);
}